// Round 1
// baseline (799.056 us; speedup 1.0000x reference)
//
#include <hip/hip_runtime.h>

// Problem constants
#define B_    2
#define T_    2048
#define HID_  2048
#define NH_   32
#define NKV_  8
#define HD_   64
#define STEPS_ 2
#define SCALE_ 0.125f

typedef float   f32x4  __attribute__((ext_vector_type(4)));
typedef __bf16  bf16x8 __attribute__((ext_vector_type(8)));
typedef unsigned short u16x8 __attribute__((ext_vector_type(8)));

__device__ __forceinline__ unsigned short f2bf(float f) {
  unsigned int u = __builtin_bit_cast(unsigned int, f);
  u = (u + 0x7fffu + ((u >> 16) & 1u)) >> 16;
  return (unsigned short)u;
}
__device__ __forceinline__ float bf2f(unsigned short h) {
  unsigned int u = ((unsigned int)h) << 16;
  return __builtin_bit_cast(float, u);
}
__device__ __forceinline__ bf16x8 frag_ld(const unsigned short* p) {
  u16x8 v = *(const u16x8*)p;
  return __builtin_bit_cast(bf16x8, v);
}
__device__ __forceinline__ f32x4 mfma16(bf16x8 a, bf16x8 b, f32x4 c) {
  return __builtin_amdgcn_mfma_f32_16x16x32_bf16(a, b, c, 0, 0, 0);
}
__device__ __forceinline__ void async_cp16(const void* g, void* l) {
  __builtin_amdgcn_global_load_lds(
      (const __attribute__((address_space(1))) void*)g,
      (__attribute__((address_space(3))) void*)l, 16, 0, 0);
}

// ---------------------------------------------------------------------------
// elementwise fp32 -> bf16 convert (float4 per thread)
__global__ __launch_bounds__(256) void convert_bf16(const float* __restrict__ in,
                                                    unsigned short* __restrict__ out,
                                                    int n4) {
  int idx = blockIdx.x * 256 + threadIdx.x;
  if (idx < n4) {
    float4 v = ((const float4*)in)[idx];
    ushort4 o;
    o.x = f2bf(v.x); o.y = f2bf(v.y); o.z = f2bf(v.z); o.w = f2bf(v.w);
    ((ushort4*)out)[idx] = o;
  }
}

// transpose + convert: in (K x N fp32 row-major) -> out (N x K bf16, ld=Kfull)
// grid (N/64, K/64); out may be an interior column block of a larger [Nfull][Kfull]
__global__ __launch_bounds__(256) void transpose_f32_bf16(const float* __restrict__ in,
                                                          unsigned short* __restrict__ out,
                                                          int K, int N) {
  __shared__ float tile[64][65];
  int n0 = blockIdx.x * 64, k0 = blockIdx.y * 64;
  int c = threadIdx.x & 63, w = threadIdx.x >> 6;
#pragma unroll
  for (int i = 0; i < 16; i++) {
    int r = w * 16 + i;
    tile[r][c] = in[(size_t)(k0 + r) * N + n0 + c];
  }
  __syncthreads();
#pragma unroll
  for (int i = 0; i < 16; i++) {
    int rr = w * 16 + i;
    out[(size_t)(n0 + rr) * 4096 + k0 + c] = f2bf(tile[c][rr]);  // ld fixed 4096? no:
  }
}

// (dedicated versions with correct ld below — the generic one above uses ld 4096)
__global__ __launch_bounds__(256) void transpose_f32_bf16_ld(const float* __restrict__ in,
                                                             unsigned short* __restrict__ out,
                                                             int K, int N, int ldo) {
  __shared__ float tile[64][65];
  int n0 = blockIdx.x * 64, k0 = blockIdx.y * 64;
  int c = threadIdx.x & 63, w = threadIdx.x >> 6;
#pragma unroll
  for (int i = 0; i < 16; i++) {
    int r = w * 16 + i;
    tile[r][c] = in[(size_t)(k0 + r) * N + n0 + c];
  }
  __syncthreads();
#pragma unroll
  for (int i = 0; i < 16; i++) {
    int rr = w * 16 + i;
    out[(size_t)(n0 + rr) * ldo + k0 + c] = f2bf(tile[c][rr]);
  }
}

// v0 (B*NH slabs of [T][D] fp32) -> v0t bf16 [B*NH][D][T]
// grid (T/64, B*NH)
__global__ __launch_bounds__(256) void transpose_v0(const float* __restrict__ v0,
                                                    unsigned short* __restrict__ v0t) {
  __shared__ float tile[64][65];
  int s0 = blockIdx.x * 64;
  int bh = blockIdx.y;
  const float* src = v0 + (size_t)bh * T_ * HD_;
  unsigned short* dst = v0t + (size_t)bh * HD_ * T_;
  int c = threadIdx.x & 63, w = threadIdx.x >> 6;
#pragma unroll
  for (int i = 0; i < 16; i++) {
    int r = w * 16 + i;                       // s-local
    tile[r][c] = src[(size_t)(s0 + r) * HD_ + c];  // c = d
  }
  __syncthreads();
#pragma unroll
  for (int i = 0; i < 16; i++) {
    int rr = w * 16 + i;                      // d
    dst[(size_t)rr * T_ + s0 + c] = f2bf(tile[c][rr]);
  }
}

// ---------------------------------------------------------------------------
// bf16 MFMA GEMM, m97-style: C(MxN fp32) = A(MxK bf16 rowmajor) * Bt(NxK bf16 rowmajor)^T
// 128x128 tile, BK=32, 256 threads (2x2 waves of 64x64)
__global__ __launch_bounds__(256) void gemm_bf16_bt(const unsigned short* __restrict__ A,
                                                    const unsigned short* __restrict__ Bt,
                                                    float* __restrict__ C,
                                                    int M, int N, int K) {
  __shared__ unsigned short sA[128 * 32];
  __shared__ unsigned short sB[128 * 32];
  const int tid = threadIdx.x;
  const int lane = tid & 63;
  const int wave = tid >> 6;
  const int m0 = blockIdx.x * 128;
  const int n0 = blockIdx.y * 128;
  const int wm = (wave >> 1) * 64;
  const int wn = (wave & 1) * 64;
  const int la = lane & 15;
  const int lq = lane >> 4;

  f32x4 acc[4][4] = {};

  const int rowc = tid >> 2;          // 0..63
  const int kc = (tid & 3) * 8;       // k element offset
  const unsigned short* gA0 = A + (size_t)(m0 + rowc) * K + kc;
  const unsigned short* gA1 = A + (size_t)(m0 + 64 + rowc) * K + kc;
  const unsigned short* gB0 = Bt + (size_t)(n0 + rowc) * K + kc;
  const unsigned short* gB1 = Bt + (size_t)(n0 + 64 + rowc) * K + kc;
  unsigned short* lA0 = &sA[wave * 512];
  unsigned short* lA1 = &sA[2048 + wave * 512];
  unsigned short* lB0 = &sB[wave * 512];
  unsigned short* lB1 = &sB[2048 + wave * 512];

  for (int k0 = 0; k0 < K; k0 += 32) {
    __syncthreads();
    async_cp16(gA0 + k0, lA0);
    async_cp16(gA1 + k0, lA1);
    async_cp16(gB0 + k0, lB0);
    async_cp16(gB1 + k0, lB1);
    __syncthreads();
    bf16x8 af[4], bfr[4];
#pragma unroll
    for (int i = 0; i < 4; i++) af[i] = frag_ld(&sA[(wm + i * 16 + la) * 32 + lq * 8]);
#pragma unroll
    for (int j = 0; j < 4; j++) bfr[j] = frag_ld(&sB[(wn + j * 16 + la) * 32 + lq * 8]);
#pragma unroll
    for (int i = 0; i < 4; i++)
#pragma unroll
      for (int j = 0; j < 4; j++) acc[i][j] = mfma16(af[i], bfr[j], acc[i][j]);
  }

#pragma unroll
  for (int i = 0; i < 4; i++) {
    int row = m0 + wm + i * 16 + lq * 4;
#pragma unroll
    for (int j = 0; j < 4; j++) {
      int col = n0 + wn + j * 16 + la;
#pragma unroll
      for (int r = 0; r < 4; r++) C[(size_t)(row + r) * N + col] = acc[i][j][r];
    }
  }
}

// ---------------------------------------------------------------------------
// RoPE: read QKV fp32, write q_b (bf16, [B][NH][T][D]) and knew (fp32, [B][NKV][T][D])
// idx = ((b*T+t)*40 + hh)*32 + i ; hh<32 -> q head, else kv head hh-32
__global__ __launch_bounds__(256) void rope_kernel(const float* __restrict__ QKV,
                                                   const int* __restrict__ pos_ids,
                                                   unsigned short* __restrict__ q_b,
                                                   float* __restrict__ knew) {
  int idx = blockIdx.x * 256 + threadIdx.x;
  const int total = B_ * T_ * (NH_ + NKV_) * 32;
  if (idx >= total) return;
  int i = idx & 31;
  int tmp = idx >> 5;
  int hh = tmp % (NH_ + NKV_);
  int bt = tmp / (NH_ + NKV_);
  int t = bt & (T_ - 1);
  int b = bt >> 11;
  int pos = pos_ids[bt] + STEPS_;
  // inv_freq = 10000^(-i/32) = 2^(-i*log2(10000)/32)
  float inv = exp2f(-(float)i * (13.287712379549449f / 32.0f));
  float ang = (float)pos * inv;
  float sn, cs;
  sincosf(ang, &sn, &cs);
  const float* rowp = QKV + (size_t)bt * 3072;
  if (hh < NH_) {
    float x1 = rowp[hh * 64 + i];
    float x2 = rowp[hh * 64 + 32 + i];
    float y1 = x1 * cs - x2 * sn;
    float y2 = x2 * cs + x1 * sn;
    size_t o = ((size_t)(b * NH_ + hh) * T_ + t) * HD_ + i;
    q_b[o] = f2bf(y1);
    q_b[o + 32] = f2bf(y2);
  } else {
    int kv = hh - NH_;
    float x1 = rowp[2048 + kv * 64 + i];
    float x2 = rowp[2048 + kv * 64 + 32 + i];
    float y1 = x1 * cs - x2 * sn;
    float y2 = x2 * cs + x1 * sn;
    size_t o = ((size_t)(b * NKV_ + kv) * T_ + t) * HD_ + i;
    knew[o] = y1;
    knew[o + 32] = y2;
  }
}

// ---------------------------------------------------------------------------
// Flash attention over k0/v0 (causal). Outputs unnormalized O and (m,l) per row.
// grid (T/64, NH, B), 256 threads. qb: [B][NH][T][D] bf16; k0b same; v0t: [B][NH][D][T] bf16
__global__ __launch_bounds__(256) void flash_kernel(const unsigned short* __restrict__ qb,
                                                    const unsigned short* __restrict__ k0b,
                                                    const unsigned short* __restrict__ v0t,
                                                    float* __restrict__ Of,
                                                    float* __restrict__ ml) {
  __shared__ unsigned short sK[64 * 64];   // [key][d]
  __shared__ unsigned short sV[64 * 64];   // [d][key]
  __shared__ unsigned short sP[4][16 * 64];  // per-wave P [m][key]

  const int tid = threadIdx.x;
  const int lane = tid & 63;
  const int wave = tid >> 6;
  const int qt = blockIdx.x, h = blockIdx.y, b = blockIdx.z;
  const int t0 = qt * 64;
  const int la = lane & 15;
  const int lq = lane >> 4;
  const size_t bh = (size_t)(b * NH_ + h);

  // q fragments (A operand), rows t0 + wave*16 + la
  const int qrow = t0 + wave * 16 + la;
  bf16x8 aq0 = frag_ld(qb + (bh * T_ + qrow) * HD_ + lq * 8);
  bf16x8 aq1 = frag_ld(qb + (bh * T_ + qrow) * HD_ + 32 + lq * 8);

  f32x4 o[4] = {};
  float m_r[4], l_r[4];
#pragma unroll
  for (int r = 0; r < 4; r++) { m_r[r] = -1e30f; l_r[r] = 0.0f; }

  const int rowc = tid >> 3;        // 0..31
  const int cc = (tid & 7) * 8;
  const unsigned short* gK = k0b + bh * T_ * HD_;
  const unsigned short* gV = v0t + bh * HD_ * T_;

  for (int kt = 0; kt <= qt; ++kt) {
    __syncthreads();
    async_cp16(gK + (size_t)(kt * 64 + rowc) * HD_ + cc, &sK[wave * 512]);
    async_cp16(gK + (size_t)(kt * 64 + 32 + rowc) * HD_ + cc, &sK[2048 + wave * 512]);
    async_cp16(gV + (size_t)rowc * T_ + kt * 64 + cc, &sV[wave * 512]);
    async_cp16(gV + (size_t)(32 + rowc) * T_ + kt * 64 + cc, &sV[2048 + wave * 512]);
    __syncthreads();

    // S = q @ K^T (16 rows x 64 keys per wave)
    f32x4 s[4];
#pragma unroll
    for (int nb = 0; nb < 4; nb++) {
      f32x4 z = {0.f, 0.f, 0.f, 0.f};
      bf16x8 b0 = frag_ld(&sK[(nb * 16 + la) * 64 + lq * 8]);
      bf16x8 b1 = frag_ld(&sK[(nb * 16 + la) * 64 + 32 + lq * 8]);
      z = mfma16(aq0, b0, z);
      z = mfma16(aq1, b1, z);
      s[nb] = z;
    }

    // scale + causal mask + row max
    float tmax[4] = {-1e30f, -1e30f, -1e30f, -1e30f};
#pragma unroll
    for (int nb = 0; nb < 4; nb++) {
#pragma unroll
      for (int r = 0; r < 4; r++) {
        float sc = s[nb][r] * SCALE_;
        int trow = t0 + wave * 16 + lq * 4 + r;
        int key = kt * 64 + nb * 16 + la;
        sc = (key <= trow) ? sc : -1e30f;
        s[nb][r] = sc;
        tmax[r] = fmaxf(tmax[r], sc);
      }
    }
#pragma unroll
    for (int off = 1; off < 16; off <<= 1) {
#pragma unroll
      for (int r = 0; r < 4; r++) tmax[r] = fmaxf(tmax[r], __shfl_xor(tmax[r], off));
    }
    float alpha[4], lsum[4] = {0.f, 0.f, 0.f, 0.f};
#pragma unroll
    for (int r = 0; r < 4; r++) {
      float mn = fmaxf(m_r[r], tmax[r]);
      alpha[r] = __expf(m_r[r] - mn);
      m_r[r] = mn;
    }
#pragma unroll
    for (int nb = 0; nb < 4; nb++) {
#pragma unroll
      for (int r = 0; r < 4; r++) {
        float p = __expf(s[nb][r] - m_r[r]);
        s[nb][r] = p;
        lsum[r] += p;
      }
    }
#pragma unroll
    for (int off = 1; off < 16; off <<= 1) {
#pragma unroll
      for (int r = 0; r < 4; r++) lsum[r] += __shfl_xor(lsum[r], off);
    }
#pragma unroll
    for (int r = 0; r < 4; r++) l_r[r] = l_r[r] * alpha[r] + lsum[r];
#pragma unroll
    for (int jd = 0; jd < 4; jd++)
#pragma unroll
      for (int r = 0; r < 4; r++) o[jd][r] *= alpha[r];

    // P -> LDS (C layout -> A layout round trip)
#pragma unroll
    for (int nb = 0; nb < 4; nb++)
#pragma unroll
      for (int r = 0; r < 4; r++)
        sP[wave][(lq * 4 + r) * 64 + nb * 16 + la] = f2bf(s[nb][r]);
    __syncthreads();

    // O += P @ V
    bf16x8 ap0 = frag_ld(&sP[wave][la * 64 + lq * 8]);
    bf16x8 ap1 = frag_ld(&sP[wave][la * 64 + 32 + lq * 8]);
#pragma unroll
    for (int jd = 0; jd < 4; jd++) {
      bf16x8 bv0 = frag_ld(&sV[(jd * 16 + la) * 64 + lq * 8]);
      bf16x8 bv1 = frag_ld(&sV[(jd * 16 + la) * 64 + 32 + lq * 8]);
      o[jd] = mfma16(ap0, bv0, o[jd]);
      o[jd] = mfma16(ap1, bv1, o[jd]);
    }
  }

  // write O (unnormalized) and m,l
#pragma unroll
  for (int jd = 0; jd < 4; jd++) {
#pragma unroll
    for (int r = 0; r < 4; r++) {
      int row = t0 + wave * 16 + lq * 4 + r;
      Of[(bh * T_ + row) * HD_ + jd * 16 + la] = o[jd][r];
    }
  }
  if (la == 0) {
#pragma unroll
    for (int r = 0; r < 4; r++) {
      int row = t0 + wave * 16 + lq * 4 + r;
      ml[(bh * T_ + row) * 2] = m_r[r];
      ml[(bh * T_ + row) * 2 + 1] = l_r[r];
    }
  }
}

// ---------------------------------------------------------------------------
// Epilogue: fold the two diagonal keys (prev_k[1], new k) into the flash result.
// One wave per (b,h,t) row; lane = d. Writes attnout bf16 [(b*T+t)][h*64+d].
__global__ __launch_bounds__(256) void attn_epilogue(const unsigned short* __restrict__ qb,
                                                     const float* __restrict__ prev_k,
                                                     const float* __restrict__ prev_v,
                                                     const float* __restrict__ knew,
                                                     const float* __restrict__ QKV,
                                                     const float* __restrict__ Of,
                                                     const float* __restrict__ ml,
                                                     unsigned short* __restrict__ attnout) {
  const int lane = threadIdx.x & 63;
  const int wave = threadIdx.x >> 6;
  const int row = blockIdx.x * 4 + wave;  // (b*NH+h)*T + t
  const int b = row >> 16;
  const int h = (row >> 11) & 31;
  const int t = row & 2047;
  const int d = lane;
  const size_t base = (size_t)row * HD_ + d;

  float q = bf2f(qb[base]);
  // prev_k/prev_v index (s=1, b, h, t, d)
  const size_t p1 = (((size_t)(STEPS_ - 1) * B_ + b) * NH_ + h) * T_ * HD_ + (size_t)t * HD_ + d;
  // note: s=1 slab starts at B*NH*T*D
  const size_t p1i = ((size_t)B_ * NH_ * T_ * HD_) + (((size_t)b * NH_ + h) * T_ + t) * HD_ + d;
  (void)p1;
  float k1 = prev_k[p1i];
  float v1 = prev_v[p1i];
  int kv = h >> 2;
  float kn = knew[(((size_t)b * NKV_ + kv) * T_ + t) * HD_ + d];
  float vn = QKV[((size_t)(b * T_ + t)) * 3072 + 2560 + kv * 64 + d];

  float e1 = q * k1, e2 = q * kn;
#pragma unroll
  for (int off = 1; off < 64; off <<= 1) {
    e1 += __shfl_xor(e1, off);
    e2 += __shfl_xor(e2, off);
  }
  e1 *= SCALE_;
  e2 *= SCALE_;

  float m = ml[(size_t)row * 2];
  float l = ml[(size_t)row * 2 + 1];
  float mf = fmaxf(m, fmaxf(e1, e2));
  float w0 = __expf(m - mf), w1 = __expf(e1 - mf), w2 = __expf(e2 - mf);
  float denom = l * w0 + w1 + w2;
  float out = (Of[base] * w0 + v1 * w1 + vn * w2) / denom;

  attnout[((size_t)(b * T_ + t)) * (NH_ * HD_) + h * HD_ + d] = f2bf(out);
}

// ---------------------------------------------------------------------------
// Workspace layout (bytes; needs ws_size >= 178,257,920)
#define OFF_QKV   ((size_t)0)          // 50,331,648  fp32 QKV [4096][3072]
#define OFF_XB    ((size_t)50331648)   // 33,554,432  bf16 X  [4096][4096]; reused as Of fp32
#define OFF_WQKVT ((size_t)83886080)   // 25,165,824  bf16 WqkvT [3072][4096]; reused as attnout bf16
#define OFF_WOT   ((size_t)109051904)  //  8,388,608  bf16 WoT [2048][2048]
#define OFF_QB    ((size_t)117440512)  // 16,777,216  bf16 q   [B][NH][T][D]
#define OFF_K0B   ((size_t)134217728)  // 16,777,216  bf16 k0  [B][NH][T][D]
#define OFF_V0T   ((size_t)150994944)  // 16,777,216  bf16 v0^T [B][NH][D][T]
#define OFF_KNEW  ((size_t)167772160)  //  8,388,608  fp32 knew [B][NKV][T][D]
#define OFF_ML    ((size_t)176160768)  //  2,097,152  fp32 (m,l) per row

extern "C" void kernel_launch(void* const* d_in, const int* in_sizes, int n_in,
                              void* d_out, int out_size, void* d_ws, size_t ws_size,
                              hipStream_t stream) {
  const float* X = (const float*)d_in[0];
  // d_in[1] attention_mask: analytically causal — not read
  const int* pos = (const int*)d_in[2];
  const float* prevk = (const float*)d_in[3];
  const float* prevv = (const float*)d_in[4];
  const float* Wq = (const float*)d_in[5];
  const float* Wk = (const float*)d_in[6];
  const float* Wv = (const float*)d_in[7];
  const float* Wo = (const float*)d_in[8];

  char* ws = (char*)d_ws;
  float* QKV = (float*)(ws + OFF_QKV);
  unsigned short* Xb = (unsigned short*)(ws + OFF_XB);
  float* Of = (float*)(ws + OFF_XB);  // alias: Xb dead after GEMM1
  unsigned short* WqkvT = (unsigned short*)(ws + OFF_WQKVT);
  unsigned short* attnout = (unsigned short*)(ws + OFF_WQKVT);  // alias: WqkvT dead after GEMM1
  unsigned short* WoT = (unsigned short*)(ws + OFF_WOT);
  unsigned short* q_b = (unsigned short*)(ws + OFF_QB);
  unsigned short* k0b = (unsigned short*)(ws + OFF_K0B);
  unsigned short* v0t = (unsigned short*)(ws + OFF_V0T);
  float* knew = (float*)(ws + OFF_KNEW);
  float* ml = (float*)(ws + OFF_ML);

  // conversions / transposes (all memory-bound)
  convert_bf16<<<16384, 256, 0, stream>>>(X, Xb, 4194304);                 // X -> bf16
  transpose_f32_bf16_ld<<<dim3(32, 64), 256, 0, stream>>>(Wq, WqkvT, 4096, 2048, 4096);
  transpose_f32_bf16_ld<<<dim3(8, 64), 256, 0, stream>>>(Wk, WqkvT + (size_t)2048 * 4096, 4096, 512, 4096);
  transpose_f32_bf16_ld<<<dim3(8, 64), 256, 0, stream>>>(Wv, WqkvT + (size_t)2560 * 4096, 4096, 512, 4096);
  transpose_f32_bf16_ld<<<dim3(32, 32), 256, 0, stream>>>(Wo, WoT, 2048, 2048, 2048);
  convert_bf16<<<8192, 256, 0, stream>>>(prevk, k0b, 2097152);             // prev_k[0] -> bf16
  transpose_v0<<<dim3(32, 64), 256, 0, stream>>>(prevv, v0t);              // prev_v[0] -> bf16 transposed

  // QKV projection
  gemm_bf16_bt<<<dim3(32, 24), 256, 0, stream>>>(Xb, WqkvT, QKV, 4096, 3072, 4096);

  // RoPE
  rope_kernel<<<20480, 256, 0, stream>>>(QKV, pos, q_b, knew);

  // flash attention over k0/v0
  flash_kernel<<<dim3(32, 32, 2), 256, 0, stream>>>(q_b, k0b, v0t, Of, ml);

  // fold diagonal keys, normalize, pack bf16
  attn_epilogue<<<32768, 256, 0, stream>>>(q_b, prevk, prevv, knew, QKV, Of, ml, attnout);

  // output projection
  gemm_bf16_bt<<<dim3(32, 16), 256, 0, stream>>>(attnout, WoT, (float*)d_out, 4096, 2048, 2048);
}

// Round 2
// 635.102 us; speedup vs baseline: 1.2582x; 1.2582x over previous
//
#include <hip/hip_runtime.h>

// Problem constants
#define B_    2
#define T_    2048
#define HID_  2048
#define NH_   32
#define NKV_  8
#define HD_   64
#define STEPS_ 2
#define SCALE_ 0.125f
// SCALE * log2(e): scores kept in exp2 domain throughout (folded into q at RoPE)
#define CSC_  0.18033688011112042f

typedef float   f32x4  __attribute__((ext_vector_type(4)));
typedef __bf16  bf16x8 __attribute__((ext_vector_type(8)));
typedef unsigned short u16x8 __attribute__((ext_vector_type(8)));

__device__ __forceinline__ unsigned short f2bf(float f) {
  unsigned int u = __builtin_bit_cast(unsigned int, f);
  u = (u + 0x7fffu + ((u >> 16) & 1u)) >> 16;
  return (unsigned short)u;
}
__device__ __forceinline__ float bf2f(unsigned short h) {
  unsigned int u = ((unsigned int)h) << 16;
  return __builtin_bit_cast(float, u);
}
__device__ __forceinline__ bf16x8 frag_ld(const unsigned short* p) {
  u16x8 v = *(const u16x8*)p;
  return __builtin_bit_cast(bf16x8, v);
}
__device__ __forceinline__ f32x4 mfma16(bf16x8 a, bf16x8 b, f32x4 c) {
  return __builtin_amdgcn_mfma_f32_16x16x32_bf16(a, b, c, 0, 0, 0);
}
__device__ __forceinline__ void async_cp16(const void* g, void* l) {
  __builtin_amdgcn_global_load_lds(
      (const __attribute__((address_space(1))) void*)g,
      (__attribute__((address_space(3))) void*)l, 16, 0, 0);
}

// ---------------------------------------------------------------------------
// elementwise fp32 -> bf16 convert (float4 per thread)
__global__ __launch_bounds__(256) void convert_bf16(const float* __restrict__ in,
                                                    unsigned short* __restrict__ out,
                                                    int n4) {
  int idx = blockIdx.x * 256 + threadIdx.x;
  if (idx < n4) {
    float4 v = ((const float4*)in)[idx];
    ushort4 o;
    o.x = f2bf(v.x); o.y = f2bf(v.y); o.z = f2bf(v.z); o.w = f2bf(v.w);
    ((ushort4*)out)[idx] = o;
  }
}

// transpose + convert: in (K x N fp32 row-major) -> out (N x K bf16, ld=ldo)
__global__ __launch_bounds__(256) void transpose_f32_bf16_ld(const float* __restrict__ in,
                                                             unsigned short* __restrict__ out,
                                                             int K, int N, int ldo) {
  __shared__ float tile[64][65];
  int n0 = blockIdx.x * 64, k0 = blockIdx.y * 64;
  int c = threadIdx.x & 63, w = threadIdx.x >> 6;
#pragma unroll
  for (int i = 0; i < 16; i++) {
    int r = w * 16 + i;
    tile[r][c] = in[(size_t)(k0 + r) * N + n0 + c];
  }
  __syncthreads();
#pragma unroll
  for (int i = 0; i < 16; i++) {
    int rr = w * 16 + i;
    out[(size_t)(n0 + rr) * ldo + k0 + c] = f2bf(tile[c][rr]);
  }
}

// v0 (B*NH slabs of [T][D] fp32) -> v0t bf16 [B*NH][D][T]
__global__ __launch_bounds__(256) void transpose_v0(const float* __restrict__ v0,
                                                    unsigned short* __restrict__ v0t) {
  __shared__ float tile[64][65];
  int s0 = blockIdx.x * 64;
  int bh = blockIdx.y;
  const float* src = v0 + (size_t)bh * T_ * HD_;
  unsigned short* dst = v0t + (size_t)bh * HD_ * T_;
  int c = threadIdx.x & 63, w = threadIdx.x >> 6;
#pragma unroll
  for (int i = 0; i < 16; i++) {
    int r = w * 16 + i;
    tile[r][c] = src[(size_t)(s0 + r) * HD_ + c];
  }
  __syncthreads();
#pragma unroll
  for (int i = 0; i < 16; i++) {
    int rr = w * 16 + i;
    dst[(size_t)rr * T_ + s0 + c] = f2bf(tile[c][rr]);
  }
}

// ---------------------------------------------------------------------------
// bf16 MFMA GEMM, m97-style: C(MxN fp32) = A(MxK) * Bt(NxK)^T
__global__ __launch_bounds__(256) void gemm_bf16_bt(const unsigned short* __restrict__ A,
                                                    const unsigned short* __restrict__ Bt,
                                                    float* __restrict__ C,
                                                    int M, int N, int K) {
  __shared__ unsigned short sA[128 * 32];
  __shared__ unsigned short sB[128 * 32];
  const int tid = threadIdx.x;
  const int lane = tid & 63;
  const int wave = tid >> 6;
  const int m0 = blockIdx.x * 128;
  const int n0 = blockIdx.y * 128;
  const int wm = (wave >> 1) * 64;
  const int wn = (wave & 1) * 64;
  const int la = lane & 15;
  const int lq = lane >> 4;

  f32x4 acc[4][4] = {};

  const int rowc = tid >> 2;
  const int kc = (tid & 3) * 8;
  const unsigned short* gA0 = A + (size_t)(m0 + rowc) * K + kc;
  const unsigned short* gA1 = A + (size_t)(m0 + 64 + rowc) * K + kc;
  const unsigned short* gB0 = Bt + (size_t)(n0 + rowc) * K + kc;
  const unsigned short* gB1 = Bt + (size_t)(n0 + 64 + rowc) * K + kc;
  unsigned short* lA0 = &sA[wave * 512];
  unsigned short* lA1 = &sA[2048 + wave * 512];
  unsigned short* lB0 = &sB[wave * 512];
  unsigned short* lB1 = &sB[2048 + wave * 512];

  for (int k0 = 0; k0 < K; k0 += 32) {
    __syncthreads();
    async_cp16(gA0 + k0, lA0);
    async_cp16(gA1 + k0, lA1);
    async_cp16(gB0 + k0, lB0);
    async_cp16(gB1 + k0, lB1);
    __syncthreads();
    bf16x8 af[4], bfr[4];
#pragma unroll
    for (int i = 0; i < 4; i++) af[i] = frag_ld(&sA[(wm + i * 16 + la) * 32 + lq * 8]);
#pragma unroll
    for (int j = 0; j < 4; j++) bfr[j] = frag_ld(&sB[(wn + j * 16 + la) * 32 + lq * 8]);
#pragma unroll
    for (int i = 0; i < 4; i++)
#pragma unroll
      for (int j = 0; j < 4; j++) acc[i][j] = mfma16(af[i], bfr[j], acc[i][j]);
  }

#pragma unroll
  for (int i = 0; i < 4; i++) {
    int row = m0 + wm + i * 16 + lq * 4;
#pragma unroll
    for (int j = 0; j < 4; j++) {
      int col = n0 + wn + j * 16 + la;
#pragma unroll
      for (int r = 0; r < 4; r++) C[(size_t)(row + r) * N + col] = acc[i][j][r];
    }
  }
}

// ---------------------------------------------------------------------------
// RoPE: read QKV fp32, write q_b (bf16 * CSC_, [B][NH][T][D]) and knew (fp32)
__global__ __launch_bounds__(256) void rope_kernel(const float* __restrict__ QKV,
                                                   const int* __restrict__ pos_ids,
                                                   unsigned short* __restrict__ q_b,
                                                   float* __restrict__ knew) {
  int idx = blockIdx.x * 256 + threadIdx.x;
  const int total = B_ * T_ * (NH_ + NKV_) * 32;
  if (idx >= total) return;
  int i = idx & 31;
  int tmp = idx >> 5;
  int hh = tmp % (NH_ + NKV_);
  int bt = tmp / (NH_ + NKV_);
  int t = bt & (T_ - 1);
  int b = bt >> 11;
  int pos = pos_ids[bt] + STEPS_;
  float inv = exp2f(-(float)i * (13.287712379549449f / 32.0f));
  float ang = (float)pos * inv;
  float sn, cs;
  sincosf(ang, &sn, &cs);
  const float* rowp = QKV + (size_t)bt * 3072;
  if (hh < NH_) {
    float x1 = rowp[hh * 64 + i];
    float x2 = rowp[hh * 64 + 32 + i];
    float y1 = (x1 * cs - x2 * sn) * CSC_;   // fold score scale into q
    float y2 = (x2 * cs + x1 * sn) * CSC_;
    size_t o = ((size_t)(b * NH_ + hh) * T_ + t) * HD_ + i;
    q_b[o] = f2bf(y1);
    q_b[o + 32] = f2bf(y2);
  } else {
    int kv = hh - NH_;
    float x1 = rowp[2048 + kv * 64 + i];
    float x2 = rowp[2048 + kv * 64 + 32 + i];
    float y1 = x1 * cs - x2 * sn;
    float y2 = x2 * cs + x1 * sn;
    size_t o = ((size_t)(b * NKV_ + kv) * T_ + t) * HD_ + i;
    knew[o] = y1;
    knew[o + 32] = y2;
  }
}

// ---------------------------------------------------------------------------
// Flash attention v2: 128 Q rows/block, 64-key tiles, double-buffered K/V via
// global_load_lds (XOR-swizzled through source-address permutation), ONE
// barrier per tile. Scores in exp2 domain (scale pre-folded into q).
// Outputs unnormalized O (fp32) and per-row (m,l) in exp2 domain.
__global__ __launch_bounds__(256, 3) void flash_kernel(const unsigned short* __restrict__ qb,
                                                       const unsigned short* __restrict__ k0b,
                                                       const unsigned short* __restrict__ v0t,
                                                       float* __restrict__ Of,
                                                       float* __restrict__ ml) {
  __shared__ unsigned short sK[2][64 * 64];   // [key][d], swizzled, 2x8KB
  __shared__ unsigned short sV[2][64 * 64];   // [d][key], swizzled, 2x8KB
  __shared__ unsigned short sP[4][16 * 72];   // per-wave P, padded stride 72

  const int tid = threadIdx.x;
  const int lane = tid & 63;
  const int wave = tid >> 6;
  const int la = lane & 15;
  const int lq = lane >> 4;
  const int swz = la & 7;

  // block decode: XCD-clustered bh (id%8 picks XCD; 8 bh per XCD), heavy qt first
  const int id = blockIdx.x;
  const int bh = (id & 7) * 8 + ((id >> 3) & 7);
  const int qt = 15 - (id >> 6);

  const size_t bhs = (size_t)bh;
  const unsigned short* gK = k0b + bhs * T_ * HD_;
  const unsigned short* gV = v0t + bhs * HD_ * T_;

  const int rb0 = qt * 128 + wave * 32;   // this wave's first Q row
  const int ktd = rb0 >> 6;               // wave's diagonal tile (same for both frags)
  const int ktmax = 2 * qt + 1;           // block's last tile (staging bound)

  // Q fragments (A operand): rows rb0 + f*16 + la
  bf16x8 aq[2][2];
#pragma unroll
  for (int f = 0; f < 2; f++) {
    const unsigned short* qp = qb + (bhs * T_ + rb0 + f * 16 + la) * HD_;
    aq[f][0] = frag_ld(qp + lq * 8);
    aq[f][1] = frag_ld(qp + 32 + lq * 8);
  }

  f32x4 o[2][4] = {};
  float m_r[2][4], l_r[2][4];
#pragma unroll
  for (int f = 0; f < 2; f++)
#pragma unroll
    for (int r = 0; r < 4; r++) { m_r[f][r] = -1e30f; l_r[f][r] = 0.0f; }

  // staging lane mapping: lane -> (row = +lane/8, swizzled col block)
  const int lrow = lane >> 3;
  const int lcb = (lane & 7) ^ lrow;   // source col-block so LDS holds XOR-swizzle

  // prologue: stage tile 0 into buf 0 (each wave stages rows wave*16..+16)
  {
    unsigned short* kd = &sK[0][wave * 1024];
    unsigned short* vd = &sV[0][wave * 1024];
    async_cp16(gK + (size_t)(wave * 16 + lrow) * HD_ + lcb * 8, kd);
    async_cp16(gK + (size_t)(wave * 16 + 8 + lrow) * HD_ + lcb * 8, kd + 512);
    async_cp16(gV + (size_t)(wave * 16 + lrow) * T_ + lcb * 8, vd);
    async_cp16(gV + (size_t)(wave * 16 + 8 + lrow) * T_ + lcb * 8, vd + 512);
  }
  __syncthreads();

  int cur = 0;
  for (int kt = 0; kt <= ktmax; ++kt) {
    // prefetch next tile into the other buffer (overlaps with compute below;
    // the end-of-iteration barrier drains it)
    if (kt < ktmax) {
      const int nk = (kt + 1) * 64;
      unsigned short* kd = &sK[cur ^ 1][wave * 1024];
      unsigned short* vd = &sV[cur ^ 1][wave * 1024];
      async_cp16(gK + (size_t)(nk + wave * 16 + lrow) * HD_ + lcb * 8, kd);
      async_cp16(gK + (size_t)(nk + wave * 16 + 8 + lrow) * HD_ + lcb * 8, kd + 512);
      async_cp16(gV + (size_t)(wave * 16 + lrow) * T_ + nk + lcb * 8, vd);
      async_cp16(gV + (size_t)(wave * 16 + 8 + lrow) * T_ + nk + lcb * 8, vd + 512);
    }

    if (kt <= ktd) {   // wave-uniform: tiles past the diagonal are fully masked
      const unsigned short* kb = &sK[cur][0];
      const unsigned short* vb = &sV[cur][0];

      // K fragments (shared by both Q fragments), swizzled read
      bf16x8 bk0[4], bk1[4];
#pragma unroll
      for (int nb = 0; nb < 4; nb++) {
        const unsigned short* rp = kb + (nb * 16 + la) * 64;
        bk0[nb] = frag_ld(rp + ((lq ^ swz) << 3));
        bk1[nb] = frag_ld(rp + (((lq + 4) ^ swz) << 3));
      }
      // S = q K^T  (exp2-domain scores; scale pre-folded)
      f32x4 s[2][4];
#pragma unroll
      for (int f = 0; f < 2; f++)
#pragma unroll
        for (int nb = 0; nb < 4; nb++) {
          f32x4 z = {0.f, 0.f, 0.f, 0.f};
          z = mfma16(aq[f][0], bk0[nb], z);
          z = mfma16(aq[f][1], bk1[nb], z);
          s[f][nb] = z;
        }

      const bool diag = (kt == ktd);
#pragma unroll
      for (int f = 0; f < 2; f++) {
        if (diag) {
#pragma unroll
          for (int nb = 0; nb < 4; nb++) {
            int key = kt * 64 + nb * 16 + la;
#pragma unroll
            for (int r = 0; r < 4; r++) {
              int row = rb0 + f * 16 + lq * 4 + r;
              s[f][nb][r] = (key <= row) ? s[f][nb][r] : -1e30f;
            }
          }
        }
        float tmax[4];
#pragma unroll
        for (int r = 0; r < 4; r++)
          tmax[r] = fmaxf(fmaxf(s[f][0][r], s[f][1][r]), fmaxf(s[f][2][r], s[f][3][r]));
#pragma unroll
        for (int off = 1; off < 16; off <<= 1)
#pragma unroll
          for (int r = 0; r < 4; r++) tmax[r] = fmaxf(tmax[r], __shfl_xor(tmax[r], off));
        float al[4], ls[4] = {0.f, 0.f, 0.f, 0.f};
#pragma unroll
        for (int r = 0; r < 4; r++) {
          float mn = fmaxf(m_r[f][r], tmax[r]);
          al[r] = exp2f(m_r[f][r] - mn);
          m_r[f][r] = mn;
        }
#pragma unroll
        for (int nb = 0; nb < 4; nb++)
#pragma unroll
          for (int r = 0; r < 4; r++) {
            float p = exp2f(s[f][nb][r] - m_r[f][r]);
            s[f][nb][r] = p;
            ls[r] += p;
          }
#pragma unroll
        for (int off = 1; off < 16; off <<= 1)
#pragma unroll
          for (int r = 0; r < 4; r++) ls[r] += __shfl_xor(ls[r], off);
#pragma unroll
        for (int r = 0; r < 4; r++) l_r[f][r] = l_r[f][r] * al[r] + ls[r];
#pragma unroll
        for (int jd = 0; jd < 4; jd++)
#pragma unroll
          for (int r = 0; r < 4; r++) o[f][jd][r] *= al[r];
      }

      // V fragments (shared by both Q fragments), swizzled read
      bf16x8 bv0[4], bv1[4];
#pragma unroll
      for (int jd = 0; jd < 4; jd++) {
        const unsigned short* rp = vb + (jd * 16 + la) * 64;
        bv0[jd] = frag_ld(rp + ((lq ^ swz) << 3));
        bv1[jd] = frag_ld(rp + (((lq + 4) ^ swz) << 3));
      }
      // P: C-layout -> LDS -> A-layout (per-wave buffer, no barrier needed)
      unsigned short* pw = &sP[wave][0];
#pragma unroll
      for (int f = 0; f < 2; f++) {
#pragma unroll
        for (int nb = 0; nb < 4; nb++)
#pragma unroll
          for (int r = 0; r < 4; r++)
            pw[(lq * 4 + r) * 72 + nb * 16 + la] = f2bf(s[f][nb][r]);
        bf16x8 ap0 = frag_ld(&pw[la * 72 + lq * 8]);
        bf16x8 ap1 = frag_ld(&pw[la * 72 + 32 + lq * 8]);
#pragma unroll
        for (int jd = 0; jd < 4; jd++) {
          o[f][jd] = mfma16(ap0, bv0[jd], o[f][jd]);
          o[f][jd] = mfma16(ap1, bv1[jd], o[f][jd]);
        }
      }
    }
    __syncthreads();   // drains prefetch (vmcnt) + protects buffer reuse
    cur ^= 1;
  }

  // write unnormalized O and (m,l)
#pragma unroll
  for (int f = 0; f < 2; f++)
#pragma unroll
    for (int jd = 0; jd < 4; jd++)
#pragma unroll
      for (int r = 0; r < 4; r++) {
        int row = rb0 + f * 16 + lq * 4 + r;
        Of[(bhs * T_ + row) * HD_ + jd * 16 + la] = o[f][jd][r];
      }
  if (la == 0) {
#pragma unroll
    for (int f = 0; f < 2; f++)
#pragma unroll
      for (int r = 0; r < 4; r++) {
        int row = rb0 + f * 16 + lq * 4 + r;
        ml[(bhs * T_ + row) * 2] = m_r[f][r];
        ml[(bhs * T_ + row) * 2 + 1] = l_r[f][r];
      }
  }
}

// ---------------------------------------------------------------------------
// Epilogue: fold the two diagonal keys (prev_k[1], new k) into the flash result.
// (m,l) and q are in exp2 domain (q pre-scaled by CSC_).
__global__ __launch_bounds__(256) void attn_epilogue(const unsigned short* __restrict__ qb,
                                                     const float* __restrict__ prev_k,
                                                     const float* __restrict__ prev_v,
                                                     const float* __restrict__ knew,
                                                     const float* __restrict__ QKV,
                                                     const float* __restrict__ Of,
                                                     const float* __restrict__ ml,
                                                     unsigned short* __restrict__ attnout) {
  const int lane = threadIdx.x & 63;
  const int wave = threadIdx.x >> 6;
  const int row = blockIdx.x * 4 + wave;  // (b*NH+h)*T + t
  const int b = row >> 16;
  const int h = (row >> 11) & 31;
  const int t = row & 2047;
  const int d = lane;
  const size_t base = (size_t)row * HD_ + d;

  float q = bf2f(qb[base]);   // includes CSC_ factor
  const size_t p1i = ((size_t)B_ * NH_ * T_ * HD_) + (((size_t)b * NH_ + h) * T_ + t) * HD_ + d;
  float k1 = prev_k[p1i];
  float v1 = prev_v[p1i];
  int kv = h >> 2;
  float kn = knew[(((size_t)b * NKV_ + kv) * T_ + t) * HD_ + d];
  float vn = QKV[((size_t)(b * T_ + t)) * 3072 + 2560 + kv * 64 + d];

  float e1 = q * k1, e2 = q * kn;
#pragma unroll
  for (int off = 1; off < 64; off <<= 1) {
    e1 += __shfl_xor(e1, off);
    e2 += __shfl_xor(e2, off);
  }

  float m = ml[(size_t)row * 2];
  float l = ml[(size_t)row * 2 + 1];
  float mf = fmaxf(m, fmaxf(e1, e2));
  float w0 = exp2f(m - mf), w1 = exp2f(e1 - mf), w2 = exp2f(e2 - mf);
  float denom = l * w0 + w1 + w2;
  float out = (Of[base] * w0 + v1 * w1 + vn * w2) / denom;

  attnout[((size_t)(b * T_ + t)) * (NH_ * HD_) + h * HD_ + d] = f2bf(out);
}

// ---------------------------------------------------------------------------
// Workspace layout (bytes; needs ws_size >= 178,257,920)
#define OFF_QKV   ((size_t)0)          // 50,331,648  fp32 QKV [4096][3072]
#define OFF_XB    ((size_t)50331648)   // 33,554,432  bf16 X; reused as Of fp32
#define OFF_WQKVT ((size_t)83886080)   // 25,165,824  bf16 WqkvT; reused as attnout
#define OFF_WOT   ((size_t)109051904)  //  8,388,608  bf16 WoT
#define OFF_QB    ((size_t)117440512)  // 16,777,216  bf16 q (pre-scaled)
#define OFF_K0B   ((size_t)134217728)  // 16,777,216  bf16 k0
#define OFF_V0T   ((size_t)150994944)  // 16,777,216  bf16 v0^T
#define OFF_KNEW  ((size_t)167772160)  //  8,388,608  fp32 knew
#define OFF_ML    ((size_t)176160768)  //  2,097,152  fp32 (m,l)

extern "C" void kernel_launch(void* const* d_in, const int* in_sizes, int n_in,
                              void* d_out, int out_size, void* d_ws, size_t ws_size,
                              hipStream_t stream) {
  const float* X = (const float*)d_in[0];
  const int* pos = (const int*)d_in[2];
  const float* prevk = (const float*)d_in[3];
  const float* prevv = (const float*)d_in[4];
  const float* Wq = (const float*)d_in[5];
  const float* Wk = (const float*)d_in[6];
  const float* Wv = (const float*)d_in[7];
  const float* Wo = (const float*)d_in[8];

  char* ws = (char*)d_ws;
  float* QKV = (float*)(ws + OFF_QKV);
  unsigned short* Xb = (unsigned short*)(ws + OFF_XB);
  float* Of = (float*)(ws + OFF_XB);
  unsigned short* WqkvT = (unsigned short*)(ws + OFF_WQKVT);
  unsigned short* attnout = (unsigned short*)(ws + OFF_WQKVT);
  unsigned short* WoT = (unsigned short*)(ws + OFF_WOT);
  unsigned short* q_b = (unsigned short*)(ws + OFF_QB);
  unsigned short* k0b = (unsigned short*)(ws + OFF_K0B);
  unsigned short* v0t = (unsigned short*)(ws + OFF_V0T);
  float* knew = (float*)(ws + OFF_KNEW);
  float* ml = (float*)(ws + OFF_ML);

  convert_bf16<<<16384, 256, 0, stream>>>(X, Xb, 4194304);
  transpose_f32_bf16_ld<<<dim3(32, 64), 256, 0, stream>>>(Wq, WqkvT, 4096, 2048, 4096);
  transpose_f32_bf16_ld<<<dim3(8, 64), 256, 0, stream>>>(Wk, WqkvT + (size_t)2048 * 4096, 4096, 512, 4096);
  transpose_f32_bf16_ld<<<dim3(8, 64), 256, 0, stream>>>(Wv, WqkvT + (size_t)2560 * 4096, 4096, 512, 4096);
  transpose_f32_bf16_ld<<<dim3(32, 32), 256, 0, stream>>>(Wo, WoT, 2048, 2048, 2048);
  convert_bf16<<<8192, 256, 0, stream>>>(prevk, k0b, 2097152);
  transpose_v0<<<dim3(32, 64), 256, 0, stream>>>(prevv, v0t);

  gemm_bf16_bt<<<dim3(32, 24), 256, 0, stream>>>(Xb, WqkvT, QKV, 4096, 3072, 4096);

  rope_kernel<<<20480, 256, 0, stream>>>(QKV, pos, q_b, knew);

  flash_kernel<<<1024, 256, 0, stream>>>(q_b, k0b, v0t, Of, ml);

  attn_epilogue<<<32768, 256, 0, stream>>>(q_b, prevk, prevv, knew, QKV, Of, ml, attnout);

  gemm_bf16_bt<<<dim3(32, 16), 256, 0, stream>>>(attnout, WoT, (float*)d_out, 4096, 2048, 2048);
}